// Round 10
// baseline (303.806 us; speedup 1.0000x reference)
//
#include <hip/hip_runtime.h>
#include <hip/hip_bf16.h>

// Problem constants (Attention_72499047957038)
#define HIDDEN 2048
#define NHEADS 32
#define NKVH   8
#define HD     64
#define BATCH  2
#define SEQ    2048
#define ROWS   (BATCH * SEQ)   // 4096
#define NQKV   3072            // 2048 Q + 512 K + 512 V
#define KCOL   2048
#define VCOL   2560

typedef __bf16 bf16x8 __attribute__((ext_vector_type(8)));
typedef __bf16 bf16x4 __attribute__((ext_vector_type(4)));
typedef float  f32x4  __attribute__((ext_vector_type(4)));
typedef short  s16x4  __attribute__((ext_vector_type(4)));
typedef short  s16x8  __attribute__((ext_vector_type(8)));

// async global->LDS, 16B per lane; LDS dest = wave-uniform base + lane*16
__device__ __forceinline__ void gl2lds16(const void* g, void* l) {
  __builtin_amdgcn_global_load_lds(
      (const __attribute__((address_space(1))) void*)g,
      (__attribute__((address_space(3))) void*)l, 16, 0, 0);
}

__device__ __forceinline__ short f2bs(float f) {
  __bf16 h = (__bf16)f;
  return __builtin_bit_cast(short, h);
}

// raw 2^x (v_exp_f32); large-negative input underflows to 0 (used for mask)
__device__ __forceinline__ float fexp2(float x) {
#if __has_builtin(__builtin_amdgcn_exp2f)
  return __builtin_amdgcn_exp2f(x);
#else
  return exp2f(x);
#endif
}

// K=16 MFMA: P (A, from S^T C-regs) x V (B). Fallback: zero-padded K=32.
__device__ __forceinline__ f32x4 mfma16(s16x4 a, s16x4 b, f32x4 c) {
#if __has_builtin(__builtin_amdgcn_mfma_f32_16x16x16bf16_1k)
  return __builtin_amdgcn_mfma_f32_16x16x16bf16_1k(a, b, c, 0, 0, 0);
#else
  s16x8 a8 = __builtin_shufflevector(a, (s16x4){0,0,0,0}, 0,1,2,3,4,5,6,7);
  s16x8 b8 = __builtin_shufflevector(b, (s16x4){0,0,0,0}, 0,1,2,3,4,5,6,7);
  a8[4]=0;a8[5]=0;a8[6]=0;a8[7]=0; b8[4]=0;b8[5]=0;b8[6]=0;b8[7]=0;
  return __builtin_amdgcn_mfma_f32_16x16x32_bf16(
      __builtin_bit_cast(bf16x8, a8), __builtin_bit_cast(bf16x8, b8), c, 0, 0, 0);
#endif
}

// ---------------------------------------------------------------------------
// prep: merged weight convert+transpose AND x fp32->bf16 convert. (as R6)
// ---------------------------------------------------------------------------
__global__ void prep(const float* __restrict__ Wq, const float* __restrict__ Wk,
                     const float* __restrict__ Wv, const float* __restrict__ Wo,
                     const float* __restrict__ x,
                     __bf16* __restrict__ dstW, __bf16* __restrict__ Xb) {
  int bid = blockIdx.x, t = threadIdx.x;
  if (bid < 2560) {
    __shared__ __bf16 tl[32][132];   // [n][k], pad 4 (stride 264B)
    int k0 = (bid & 15) * 128;
    int n0 = (bid >> 4) * 32;
    const float* src;
    int N, c0;
    if (n0 < 2048)      { src = Wq; N = 2048; c0 = n0; }
    else if (n0 < 2560) { src = Wk; N = 512;  c0 = n0 - 2048; }
    else if (n0 < 3072) { src = Wv; N = 512;  c0 = n0 - 2560; }
    else                { src = Wo; N = 2048; c0 = n0 - 3072; }
    int rr = t >> 3;          // 0..31 row within pass
    int cc = (t & 7) * 4;     // col group
#pragma unroll
    for (int pass = 0; pass < 4; ++pass) {
      int k = pass * 32 + rr;
      float4 v = *(const float4*)(src + (size_t)(k0 + k) * N + c0 + cc);
      tl[cc + 0][k] = (__bf16)v.x;
      tl[cc + 1][k] = (__bf16)v.y;
      tl[cc + 2][k] = (__bf16)v.z;
      tl[cc + 3][k] = (__bf16)v.w;
    }
    __syncthreads();
    int n = t >> 4;           // 0..15
    int ch = t & 15;          // k-chunk (8 elems = 16B)
#pragma unroll
    for (int it = 0; it < 2; ++it) {
      int nn = n + it * 16;
      s16x4 lo = *(const s16x4*)(&tl[nn][ch * 8]);
      s16x4 hi = *(const s16x4*)(&tl[nn][ch * 8 + 4]);
      s16x8 o = __builtin_shufflevector(lo, hi, 0, 1, 2, 3, 4, 5, 6, 7);
      *(s16x8*)(dstW + (size_t)(n0 + nn) * HIDDEN + k0 + ch * 8) = o;
    }
  } else {
    size_t i = (size_t)(bid - 2560) * 256 + t;   // 16 elems per thread
    const float4* s = (const float4*)(x + i * 16);
    float4 a = s[0], b = s[1], c = s[2], d = s[3];
    bf16x8 o0, o1;
    o0[0] = (__bf16)a.x; o0[1] = (__bf16)a.y; o0[2] = (__bf16)a.z; o0[3] = (__bf16)a.w;
    o0[4] = (__bf16)b.x; o0[5] = (__bf16)b.y; o0[6] = (__bf16)b.z; o0[7] = (__bf16)b.w;
    o1[0] = (__bf16)c.x; o1[1] = (__bf16)c.y; o1[2] = (__bf16)c.z; o1[3] = (__bf16)c.w;
    o1[4] = (__bf16)d.x; o1[5] = (__bf16)d.y; o1[6] = (__bf16)d.z; o1[7] = (__bf16)d.w;
    *(bf16x8*)(Xb + i * 16)     = o0;
    *(bf16x8*)(Xb + i * 16 + 8) = o1;
  }
}

// ---------------------------------------------------------------------------
// QKV GEMM, 256x256 tile, BK=64, 512 thr = 8 waves (2Mx4N).
// R10: 4-PHASE LOCKSTEP per K-tile (T3) on top of R9's counted vmcnt (T4).
// Phase (mh,ks) = { issue 2 gl2lds of tile kt+1 | minimal ds_read (B-frags
// held across mh-phases: 8/4/8/4 b128 = 24/K-tile, the minimum) | setprio(1)
// 16 MFMA setprio(0) | s_barrier }. Publish barrier + vmcnt(2) only at
// phase 0 (counted, never 0 mid-loop). sched_barrier(0) pins phase edges.
// Waves interleave roles across phases -> T5 setprio pays (m218b structure).
// LDS XOR-swizzle chunk^=(row&7) src-side (conflicts=0, HW-verified R8/R9).
// Grid 192 (1/CU). Epilogue (ROPE/Vt) HW-verified R8/R9.
// ---------------------------------------------------------------------------
__launch_bounds__(512, 2)
__global__ void gemm_qkv256(const __bf16* __restrict__ A, const __bf16* __restrict__ Bt,
                            __bf16* __restrict__ C,
                            const int* __restrict__ pos_ids, __bf16* __restrict__ Vt) {
  __shared__ __bf16 As[2][16384];   // [slot][256r][64k], swizzled chunks (64KB)
  __shared__ __bf16 Bs[2][16384];   // (64KB)

  int id = blockIdx.x;
  int xcd = id & 7, j = id >> 3;          // j 0..23
  int bm = xcd * 2 + (j >= 12 ? 1 : 0);   // 0..15
  int bn = (j >= 12) ? (j - 12) : j;      // 0..11

  int t = threadIdx.x;
  int wave = t >> 6, lane = t & 63, l16 = lane & 15, quad = lane >> 4;
  int wml = (wave & 1) * 128;            // M offset in tile
  int wnl = (wave >> 1) * 64;            // N offset in tile

  // staging map: instr jj covers rows jj*64..+63; wave w rows +w*8..+7;
  // lane l: row jj*64 + w*8 + (l>>3), LDS chunk l&7 <- global chunk (l&7)^(l>>3)
  int srow = wave * 8 + (lane >> 3);
  int csrc = ((lane & 7) ^ (lane >> 3)) * 8;
  const __bf16* Ag = A  + (size_t)(bm * 256 + srow) * HIDDEN + csrc;
  const __bf16* Bg = Bt + (size_t)(bn * 256 + srow) * HIDDEN + csrc;

  f32x4 acc[8][4] = {};

  // read swizzle chunks (row&7 = l16&7 for all fragment rows)
  int ch0 = ((quad ^ (l16 & 7))) * 8;        // ks=0: global chunk quad
  int ch1 = (((4 + quad) ^ (l16 & 7))) * 8;  // ks=1: global chunk 4+quad

  // prologue: stage K-tile 0 -> slot 0 (8 gl2lds, left in flight)
#pragma unroll
  for (int jj = 0; jj < 4; ++jj) {
    gl2lds16(Ag + (size_t)jj * 64 * HIDDEN, &As[0][(jj * 64 + wave * 8) * 64]);
    gl2lds16(Bg + (size_t)jj * 64 * HIDDEN, &Bs[0][(jj * 64 + wave * 8) * 64]);
  }

  for (int kt = 0; kt < 32; ++kt) {
    int s = kt & 1;
    bool pre = (kt < 31);
    const __bf16* Agk = Ag + (size_t)(kt + 1) * 64;
    const __bf16* Bgk = Bg + (size_t)(kt + 1) * 64;
    __bf16* Asn = &As[s ^ 1][wave * 512];
    __bf16* Bsn = &Bs[s ^ 1][wave * 512];
    const __bf16* Asc = &As[s][0];
    const __bf16* Bsc = &Bs[s][0];

    bf16x8 bfr[4], af[4];

    // ---------- phase 0: (mh=0, ks=0) + publish tile kt ----------
    if (pre) {
      gl2lds16(Agk, Asn);
      gl2lds16(Bgk, Bsn);
      asm volatile("s_waitcnt vmcnt(2)" ::: "memory");   // tile kt landed
    } else {
      asm volatile("s_waitcnt vmcnt(0)" ::: "memory");
    }
    __builtin_amdgcn_s_barrier();
    __builtin_amdgcn_sched_barrier(0);
#pragma unroll
    for (int n = 0; n < 4; ++n)
      bfr[n] = *(const bf16x8*)(Bsc + (wnl + n * 16 + l16) * 64 + ch0);
#pragma unroll
    for (int m = 0; m < 4; ++m)
      af[m] = *(const bf16x8*)(Asc + (wml + m * 16 + l16) * 64 + ch0);
    __builtin_amdgcn_s_setprio(1);
#pragma unroll
    for (int m = 0; m < 4; ++m)
#pragma unroll
      for (int n = 0; n < 4; ++n)
        acc[m][n] = __builtin_amdgcn_mfma_f32_16x16x32_bf16(af[m], bfr[n], acc[m][n], 0, 0, 0);
    __builtin_amdgcn_s_setprio(0);
    __builtin_amdgcn_sched_barrier(0);
    __builtin_amdgcn_s_barrier();
    __builtin_amdgcn_sched_barrier(0);

    // ---------- phase 1: (mh=1, ks=0), B held ----------
    if (pre) {
      gl2lds16(Agk + (size_t)64 * HIDDEN, Asn + 4096);
      gl2lds16(Bgk + (size_t)64 * HIDDEN, Bsn + 4096);
    }
#pragma unroll
    for (int m = 0; m < 4; ++m)
      af[m] = *(const bf16x8*)(Asc + (wml + 64 + m * 16 + l16) * 64 + ch0);
    __builtin_amdgcn_s_setprio(1);
#pragma unroll
    for (int m = 0; m < 4; ++m)
#pragma unroll
      for (int n = 0; n < 4; ++n)
        acc[4 + m][n] = __builtin_amdgcn_mfma_f32_16x16x32_bf16(af[m], bfr[n], acc[4 + m][n], 0, 0, 0);
    __builtin_amdgcn_s_setprio(0);
    __builtin_amdgcn_sched_barrier(0);
    __builtin_amdgcn_s_barrier();
    __builtin_amdgcn_sched_barrier(0);

    // ---------- phase 2: (mh=0, ks=1) ----------
    if (pre) {
      gl2lds16(Agk + (size_t)128 * HIDDEN, Asn + 8192);
      gl2lds16(Bgk + (size_t)128 * HIDDEN, Bsn + 8192);
    }
#pragma unroll
    for (int n = 0; n < 4; ++n)
      bfr[n] = *(const bf16x8*)(Bsc + (wnl + n * 16 + l16) * 64 + ch1);
#pragma unroll
    for (int m = 0; m < 4; ++m)
      af[m] = *(const bf16x8*)(Asc + (wml + m * 16 + l16) * 64 + ch1);
    __builtin_amdgcn_s_setprio(1);
#pragma unroll
    for (int m = 0; m < 4; ++m)
#pragma unroll
      for (int n = 0; n < 4; ++n)
        acc[m][n] = __builtin_amdgcn_mfma_f32_16x16x32_bf16(af[m], bfr[n], acc[m][n], 0, 0, 0);
    __builtin_amdgcn_s_setprio(0);
    __builtin_amdgcn_sched_barrier(0);
    __builtin_amdgcn_s_barrier();
    __builtin_amdgcn_sched_barrier(0);

    // ---------- phase 3: (mh=1, ks=1), B held ----------
    if (pre) {
      gl2lds16(Agk + (size_t)192 * HIDDEN, Asn + 12288);
      gl2lds16(Bgk + (size_t)192 * HIDDEN, Bsn + 12288);
    }
#pragma unroll
    for (int m = 0; m < 4; ++m)
      af[m] = *(const bf16x8*)(Asc + (wml + 64 + m * 16 + l16) * 64 + ch1);
    __builtin_amdgcn_s_setprio(1);
#pragma unroll
    for (int m = 0; m < 4; ++m)
#pragma unroll
      for (int n = 0; n < 4; ++n)
        acc[4 + m][n] = __builtin_amdgcn_mfma_f32_16x16x32_bf16(af[m], bfr[n], acc[4 + m][n], 0, 0, 0);
    __builtin_amdgcn_s_setprio(0);
    __builtin_amdgcn_sched_barrier(0);
    __builtin_amdgcn_s_barrier();   // slot s readers done -> kt+2 may stage here
    __builtin_amdgcn_sched_barrier(0);
  }

  int headidx = bn * 4 + (wave >> 1);   // 64-col head index, wave-uniform
  if (headidx >= 40) {
    // V head: write transposed into Vt (4 consecutive s per store)
    int hk = headidx - 40;
#pragma unroll
    for (int m = 0; m < 8; ++m) {
      int gr0 = bm * 256 + wml + m * 16 + quad * 4;
      int b = gr0 >> 11, sq = gr0 & 2047;
#pragma unroll
      for (int n = 0; n < 4; ++n) {
        int d = n * 16 + l16;
        bf16x4 w;
#pragma unroll
        for (int r = 0; r < 4; ++r) w[r] = (__bf16)acc[m][n][r];
        *(bf16x4*)(Vt + ((size_t)(b * NKVH + hk) * HD + d) * SEQ + sq) = w;
      }
    }
    return;
  }
  // Q/K heads: rotary (pairs (n, n+2) = cols c, c+32; freq idx l16 + 16*(n&1))
  float invrev0 = __expf(-(float)l16 * 0.28782313662425574f) * 0.15915494309189535f;
  float invrev1 = __expf(-(float)(l16 + 16) * 0.28782313662425574f) * 0.15915494309189535f;
#pragma unroll
  for (int m = 0; m < 8; ++m)
#pragma unroll
    for (int r = 0; r < 4; ++r) {
      int gr = bm * 256 + wml + m * 16 + quad * 4 + r;
      float pos = (float)pos_ids[gr];
      float rv0 = pos * invrev0; rv0 -= floorf(rv0);
      float rv1 = pos * invrev1; rv1 -= floorf(rv1);
      float a0 = rv0 * 6.283185307179586f, a1 = rv1 * 6.283185307179586f;
      float s0 = __sinf(a0), c0 = __cosf(a0);
      float s1 = __sinf(a1), c1 = __cosf(a1);
      float x0 = acc[m][0][r], x2 = acc[m][2][r];
      acc[m][0][r] = x0 * c0 - x2 * s0;
      acc[m][2][r] = x2 * c0 + x0 * s0;
      float x1 = acc[m][1][r], x3 = acc[m][3][r];
      acc[m][1][r] = x1 * c1 - x3 * s1;
      acc[m][3][r] = x3 * c1 + x1 * s1;
    }
#pragma unroll
  for (int m = 0; m < 8; ++m)
#pragma unroll
    for (int n = 0; n < 4; ++n)
#pragma unroll
      for (int r = 0; r < 4; ++r)
        C[(size_t)(bm * 256 + wml + m * 16 + quad * 4 + r) * NQKV +
          (bn * 256 + wnl + n * 16 + l16)] = (__bf16)acc[m][n][r];
}

// ---------------------------------------------------------------------------
// GEMM: C[M][N] = A[M][K] @ Bt[N][K]^T  (bf16 in, fp32 accum, OutT out)
// 128x128 tile, BK=64 as 2x32 panels, XCD-swizzled 1D grid. (out-proj only)
// ---------------------------------------------------------------------------
template <typename OutT>
__launch_bounds__(256, 2)
__global__ void gemm_bt(const __bf16* __restrict__ A, const __bf16* __restrict__ Bt,
                        OutT* __restrict__ C, int M, int N, int K) {
  __shared__ __bf16 As[2][128 * 32];
  __shared__ __bf16 Bs[2][128 * 32];
  int id = blockIdx.x;
  int bm = (id & 7) * 4 + ((id >> 3) & 3);
  int bn = id >> 5;
  int t = threadIdx.x;
  int wave = t >> 6, lane = t & 63, l16 = lane & 15, quad = lane >> 4;
  int wm = (wave >> 1) * 64, wn = (wave & 1) * 64;

  f32x4 acc[4][4] = {};

  int arow = t >> 2;            // 0..63
  int ac   = (t & 3) * 8;       // 0,8,16,24
  const __bf16* Ag = A  + (size_t)(bm * 128 + arow) * K + ac;
  const __bf16* Bg = Bt + (size_t)(bn * 128 + arow) * K + ac;
  int woff = wave * 512;

  for (int k0 = 0; k0 < K; k0 += 64) {
    __syncthreads();
    gl2lds16(Ag + k0,                      &As[0][woff]);
    gl2lds16(Ag + (size_t)64 * K + k0,      &As[0][2048 + woff]);
    gl2lds16(Ag + k0 + 32,                 &As[1][woff]);
    gl2lds16(Ag + (size_t)64 * K + k0 + 32, &As[1][2048 + woff]);
    gl2lds16(Bg + k0,                      &Bs[0][woff]);
    gl2lds16(Bg + (size_t)64 * K + k0,      &Bs[0][2048 + woff]);
    gl2lds16(Bg + k0 + 32,                 &Bs[1][woff]);
    gl2lds16(Bg + (size_t)64 * K + k0 + 32, &Bs[1][2048 + woff]);
    __syncthreads();

#pragma unroll
    for (int ks = 0; ks < 2; ++ks) {
      bf16x8 af[4], bfr[4];
#pragma unroll
      for (int i = 0; i < 4; ++i) {
        af[i]  = *(const bf16x8*)(&As[ks][(wm + i * 16 + l16) * 32 + quad * 8]);
        bfr[i] = *(const bf16x8*)(&Bs[ks][(wn + i * 16 + l16) * 32 + quad * 8]);
      }
#pragma unroll
      for (int i = 0; i < 4; ++i)
#pragma unroll
        for (int j = 0; j < 4; ++j)
          acc[i][j] = __builtin_amdgcn_mfma_f32_16x16x32_bf16(af[i], bfr[j], acc[i][j], 0, 0, 0);
    }
  }

#pragma unroll
  for (int i = 0; i < 4; ++i)
#pragma unroll
    for (int j = 0; j < 4; ++j)
#pragma unroll
      for (int r = 0; r < 4; ++r)
        C[(size_t)(bm * 128 + wm + i * 16 + quad * 4 + r) * N +
          (bn * 128 + wn + j * 16 + l16)] = (OutT)acc[i][j][r];
}

// ---------------------------------------------------------------------------
// Flash attention (causal, GQA) — unchanged from R6 (conflict-free verified).
// ---------------------------------------------------------------------------
__launch_bounds__(256, 4)
__global__ void flash_attn(const __bf16* __restrict__ QKV, const __bf16* __restrict__ Vt,
                           __bf16* __restrict__ O) {
  int wgid = blockIdx.x + 64 * (blockIdx.y + 8 * (int)blockIdx.z);
  int xcd  = wgid & 7;          // hardware XCD (round-robin on linear id)
  int j    = wgid >> 3;         // 0..127: position within XCD's sequence
  int G    = j >> 6;            // which of this XCD's 2 KV groups
  int gid  = xcd * 2 + G;       // (b,hk) group id 0..15
  int b    = gid >> 3;
  int hk   = gid & 7;
  int r    = j & 63;            // 0..63: 4 heads x 16 M, balance-coded
  int b0   = r & 1, b5 = (r >> 5) & 1;
  int h    = hk * 4 + b0 + 2 * b5;            // query head
  int M0   = (r >> 1) & 15;
  int M    = (b0 ^ b5) ? (15 - M0) : M0;      // q-block index 0..15
  int NT   = 2 * M + 2;                       // kv-tiles (= stages)

  int t = threadIdx.x;
  int wave = t >> 6, lane = t & 63, l16 = lane & 15, quad = lane >> 4;

  __shared__ __bf16 Ks[2][2][64 * 32];   // [buf][d-half][kr][32]  16KB
  __shared__ __bf16 Vs[2][4096];         // [buf][s4][colswz][4]   16KB

  const __bf16* Kbase = QKV + (size_t)(b * SEQ) * NQKV + KCOL + hk * HD;
  const __bf16* VtB   = Vt + (size_t)(b * NKVH + hk) * HD * SEQ;

  // K staging: row kr, SWIZZLED global col chunk (slot ^ (row>>1)&3)
  int kr  = wave * 16 + (lane >> 2);
  int kcs = ((lane & 3) ^ ((lane >> 3) & 3)) * 8;
  // K read: LDS slot quad ^ ((row>>1)&3), row = nt*16+l16
  int rq  = (quad ^ ((l16 >> 1) & 3)) * 8;

  // V staging maps (per wave: rows wave*16..+15, 16 s per lane)
  int vd   = kr;                       // Vt d-row 0..63
  int vsc  = (lane & 3) * 16;          // s-chunk start
  int vs4w = (lane & 3) * 4;           // first s4 this lane writes
  int vcw4 = (vd ^ (4 * (lane & 3))) * 4;   // swizzled col*4 for writes

  const s16x4 vones = { (short)0x3F80, (short)0x3F80, (short)0x3F80, (short)0x3F80 };

  // Q fragments for both q-halves, pre-scaled by (1/8)*log2(e)
  bf16x8 qfrag[2][2];   // [qi][ks]
#pragma unroll
  for (int qi = 0; qi < 2; ++qi) {
    const __bf16* qp = QKV + (size_t)(b * SEQ + M * 128 + qi * 64 + wave * 16 + l16) * NQKV
                     + h * HD + quad * 8;
    bf16x8 q0 = *(const bf16x8*)qp;
    bf16x8 q1 = *(const bf16x8*)(qp + 32);
#pragma unroll
    for (int e = 0; e < 8; ++e) {
      qfrag[qi][0][e] = (__bf16)((float)q0[e] * 0.18033688011112042f);
      qfrag[qi][1][e] = (__bf16)((float)q1[e] * 0.18033688011112042f);
    }
  }

  f32x4 lacc[2] = { {0.f,0.f,0.f,0.f}, {0.f,0.f,0.f,0.f} };
  f32x4 oacc[2][4];
#pragma unroll
  for (int qi = 0; qi < 2; ++qi)
#pragma unroll
    for (int dt = 0; dt < 4; ++dt) oacc[qi][dt] = (f32x4){0.f, 0.f, 0.f, 0.f};

  // prologue: stage tile 0 into buf 0
  {
    const __bf16* kp = Kbase + (size_t)kr * NQKV + kcs;
    gl2lds16(kp,      &Ks[0][0][wave * 512]);
    gl2lds16(kp + 32, &Ks[0][1][wave * 512]);
    const __bf16* vp = VtB + (size_t)vd * SEQ + vsc;
    s16x8 v0 = __builtin_bit_cast(s16x8, *(const bf16x8*)vp);
    s16x8 v1 = __builtin_bit_cast(s16x8, *(const bf16x8*)(vp + 8));
    *(s16x4*)(&Vs[0][(vs4w + 0) * 256 + vcw4]) = __builtin_shufflevector(v0, v0, 0, 1, 2, 3);
    *(s16x4*)(&Vs[0][(vs4w + 1) * 256 + vcw4]) = __builtin_shufflevector(v0, v0, 4, 5, 6, 7);
    *(s16x4*)(&Vs[0][(vs4w + 2) * 256 + vcw4]) = __builtin_shufflevector(v1, v1, 0, 1, 2, 3);
    *(s16x4*)(&Vs[0][(vs4w + 3) * 256 + vcw4]) = __builtin_shufflevector(v1, v1, 4, 5, 6, 7);
  }

  for (int kt = 0; kt < NT; ++kt) {
    int buf = kt & 1;
    __syncthreads();   // prefetch of tile kt drained; buf^1 free to fill

    bool pre = (kt < NT - 1);   // also == "qi0 active" (qi0 needs kt <= 2M)
    s16x8 pv0, pv1;
    if (pre) {
      const __bf16* kp = Kbase + (size_t)((kt + 1) * 64 + kr) * NQKV + kcs;
      gl2lds16(kp,      &Ks[buf ^ 1][0][wave * 512]);
      gl2lds16(kp + 32, &Ks[buf ^ 1][1][wave * 512]);
      const __bf16* vp = VtB + (size_t)vd * SEQ + (kt + 1) * 64 + vsc;
      pv0 = __builtin_bit_cast(s16x8, *(const bf16x8*)vp);
      pv1 = __builtin_bit_cast(s16x8, *(const bf16x8*)(vp + 8));
    }

    // ---- S^T = K Q^T : D[k=quad*4+r][q=l16], both q-halves share kf ----
    f32x4 s0[4], s1[4];
#pragma unroll
    for (int nt = 0; nt < 4; ++nt) {
      s0[nt] = (f32x4){0.f, 0.f, 0.f, 0.f};
      s1[nt] = (f32x4){0.f, 0.f, 0.f, 0.f};
    }
#pragma unroll
    for (int ks = 0; ks < 2; ++ks) {
      bf16x8 kf[4];
#pragma unroll
      for (int nt = 0; nt < 4; ++nt)
        kf[nt] = *(const bf16x8*)(&Ks[buf][ks][(nt * 16 + l16) * 32 + rq]);
#pragma unroll
      for (int nt = 0; nt < 4; ++nt)
        s1[nt] = __builtin_amdgcn_mfma_f32_16x16x32_bf16(kf[nt], qfrag[1][ks], s1[nt], 0, 0, 0);
      if (pre) {
#pragma unroll
        for (int nt = 0; nt < 4; ++nt)
          s0[nt] = __builtin_amdgcn_mfma_f32_16x16x32_bf16(kf[nt], qfrag[0][ks], s0[nt], 0, 0, 0);
      }
    }

    // ---- p = exp2(s^T); pack A-frags for K=16 PV ----
    s16x4 af0[4], af1[4];
    {
      int qg = wave * 16 + l16;
      if (kt == NT - 1) {
#pragma unroll
        for (int nt = 0; nt < 4; ++nt)
#pragma unroll
          for (int rr = 0; rr < 4; ++rr) {
            int kg = nt * 16 + quad * 4 + rr;
            af1[nt][rr] = f2bs(fexp2((kg > qg) ? -1e30f : s1[nt][rr]));
          }
      } else {
#pragma unroll
        for (int nt = 0; nt < 4; ++nt)
#pragma unroll
          for (int rr = 0; rr < 4; ++rr)
            af1[nt][rr] = f2bs(fexp2(s1[nt][rr]));
      }
      if (pre) {
        if (kt == NT - 2) {
#pragma unroll
          for (int nt = 0; nt < 4; ++nt)
#pragma unroll
            for (int rr = 0; rr < 4; ++rr) {
              int kg = nt * 16 + quad * 4 + rr;
              af0[nt][rr] = f2bs(fexp2((kg > qg) ? -1e30f : s0[nt][rr]));
            }
        } else {
#pragma unroll
          for (int nt = 0; nt < 4; ++nt)
#pragma unroll
            for (int rr = 0; rr < 4; ++rr)
              af0[nt][rr] = f2bs(fexp2(s0[nt][rr]));
        }
      }
    }

    // ---- O += P @ V ; row-sum += P @ 1 (both q-halves share vf) ----
#pragma unroll
    for (int nt = 0; nt < 4; ++nt) {
      s16x4 vf[4];
#pragma unroll
      for (int dt = 0; dt < 4; ++dt)
        vf[dt] = *(const s16x4*)(&Vs[buf][(nt * 4 + quad) * 256 +
                                          (((dt * 16 + l16) ^ (nt * 4)) * 4)]);
#pragma unroll
      for (int dt = 0; dt < 4; ++dt)
        oacc[1][dt] = mfma16(af1[nt], vf[dt], oacc[1][dt]);
      lacc[1] = mfma16(af1[nt], vones, lacc[1]);
      if (pre) {
#pragma unroll
        for (int dt = 0; dt < 4; ++dt)
          oacc[0][dt] = mfma16(af0[nt], vf[dt], oacc[0][dt]);
        lacc[0] = mfma16(af0[nt], vones, lacc[0]);
      }
    }

    // ---- deferred V ds_write for tile kt+1 (loads had whole tile) ----
    if (pre) {
      *(s16x4*)(&Vs[buf ^ 1][(vs4w + 0) * 256 + vcw4]) = __builtin_shufflevector(pv0, pv0, 0, 1, 2, 3);
      *(s16x4*)(&Vs[buf ^ 1][(vs4w + 1) * 256 + vcw4]) = __builtin_shufflevector(pv0, pv0, 4, 5, 6, 7);
      *(s16x4*)(&Vs[buf ^ 1][(vs4w + 2) * 256 + vcw4]) = __builtin_shufflevector(pv1, pv1, 0, 1, 2, 3);
      *(s16x4*)(&Vs[buf ^ 1][(vs4w + 3) * 256 + vcw4]) = __builtin_shufflevector(pv1, pv1, 4, 5, 6, 7);
    }
  }

  // epilogue: lane-local normalization (lacc C-layout == oacc C-layout)
#pragma unroll
  for (int qi = 0; qi < 2; ++qi) {
#pragma unroll
    for (int rr = 0; rr < 4; ++rr) {
      float inv = 1.0f / lacc[qi][rr];
#pragma unroll
      for (int dt = 0; dt < 4; ++dt) {
        float o = oacc[qi][dt][rr] * inv;
        O[(size_t)(b * SEQ + M * 128 + qi * 64 + wave * 16 + quad * 4 + rr) * HIDDEN +
          h * HD + dt * 16 + l16] = (__bf16)o;
      }
    }
  }
}

// ---------------------------------------------------------------------------
extern "C" void kernel_launch(void* const* d_in, const int* in_sizes, int n_in,
                              void* d_out, int out_size, void* d_ws, size_t ws_size,
                              hipStream_t stream) {
  const float* x  = (const float*)d_in[0];
  const float* Wq = (const float*)d_in[1];
  const float* Wk = (const float*)d_in[2];
  const float* Wv = (const float*)d_in[3];
  const float* Wo = (const float*)d_in[4];
  const int* pos  = (const int*)d_in[5];

  __bf16* Wqkvt = (__bf16*)d_ws;                       // [5120][2048]: Wqkv^T | Wo^T
  __bf16* Wot   = Wqkvt + (size_t)NQKV * HIDDEN;
  __bf16* Xb    = Wot + (size_t)HIDDEN * HIDDEN;
  __bf16* QKV   = Xb + (size_t)ROWS * HIDDEN;
  __bf16* Oat   = QKV + (size_t)ROWS * NQKV;

  // Vt: own region if workspace allows (removes the Xb-alias write/read race
  // inside the QKV GEMM); alias fallback preserves old behavior otherwise.
  size_t need = ((size_t)(NQKV + HIDDEN) * HIDDEN + 2 * (size_t)ROWS * HIDDEN +
                 (size_t)ROWS * NQKV + (size_t)BATCH * NKVH * HD * SEQ) * sizeof(__bf16);
  __bf16* Vt = (ws_size >= need) ? (Oat + (size_t)ROWS * HIDDEN) : Xb;

  prep<<<dim3(4608), 256, 0, stream>>>(Wq, Wk, Wv, Wo, x, Wqkvt, Xb);

  gemm_qkv256<<<dim3(192), 512, 0, stream>>>(Xb, Wqkvt, QKV, pos, Vt);

  flash_attn<<<dim3(64, NKVH, BATCH), 256, 0, stream>>>(QKV, Vt, Oat);

  gemm_bt<float><<<dim3(512), 256, 0, stream>>>(
      Oat, Wot, (float*)d_out, ROWS, HIDDEN, HIDDEN);
}

// Round 11
// 268.219 us; speedup vs baseline: 1.1327x; 1.1327x over previous
//
#include <hip/hip_runtime.h>
#include <hip/hip_bf16.h>

// Problem constants (Attention_72499047957038)
#define HIDDEN 2048
#define NHEADS 32
#define NKVH   8
#define HD     64
#define BATCH  2
#define SEQ    2048
#define ROWS   (BATCH * SEQ)   // 4096
#define NQKV   3072            // 2048 Q + 512 K + 512 V
#define KCOL   2048
#define VCOL   2560

typedef __bf16 bf16x8 __attribute__((ext_vector_type(8)));
typedef __bf16 bf16x4 __attribute__((ext_vector_type(4)));
typedef float  f32x4  __attribute__((ext_vector_type(4)));
typedef short  s16x4  __attribute__((ext_vector_type(4)));
typedef short  s16x8  __attribute__((ext_vector_type(8)));

// async global->LDS, 16B per lane; LDS dest = wave-uniform base + lane*16
__device__ __forceinline__ void gl2lds16(const void* g, void* l) {
  __builtin_amdgcn_global_load_lds(
      (const __attribute__((address_space(1))) void*)g,
      (__attribute__((address_space(3))) void*)l, 16, 0, 0);
}

__device__ __forceinline__ short f2bs(float f) {
  __bf16 h = (__bf16)f;
  return __builtin_bit_cast(short, h);
}

// raw 2^x (v_exp_f32); large-negative input underflows to 0 (used for mask)
__device__ __forceinline__ float fexp2(float x) {
#if __has_builtin(__builtin_amdgcn_exp2f)
  return __builtin_amdgcn_exp2f(x);
#else
  return exp2f(x);
#endif
}

// K=16 MFMA: P (A, from S^T C-regs) x V (B). Fallback: zero-padded K=32.
__device__ __forceinline__ f32x4 mfma16(s16x4 a, s16x4 b, f32x4 c) {
#if __has_builtin(__builtin_amdgcn_mfma_f32_16x16x16bf16_1k)
  return __builtin_amdgcn_mfma_f32_16x16x16bf16_1k(a, b, c, 0, 0, 0);
#else
  s16x8 a8 = __builtin_shufflevector(a, (s16x4){0,0,0,0}, 0,1,2,3,4,5,6,7);
  s16x8 b8 = __builtin_shufflevector(b, (s16x4){0,0,0,0}, 0,1,2,3,4,5,6,7);
  a8[4]=0;a8[5]=0;a8[6]=0;a8[7]=0; b8[4]=0;b8[5]=0;b8[6]=0;b8[7]=0;
  return __builtin_amdgcn_mfma_f32_16x16x32_bf16(
      __builtin_bit_cast(bf16x8, a8), __builtin_bit_cast(bf16x8, b8), c, 0, 0, 0);
#endif
}

// ---------------------------------------------------------------------------
// prep: merged weight convert+transpose AND x fp32->bf16 convert. (as R6)
// ---------------------------------------------------------------------------
__global__ void prep(const float* __restrict__ Wq, const float* __restrict__ Wk,
                     const float* __restrict__ Wv, const float* __restrict__ Wo,
                     const float* __restrict__ x,
                     __bf16* __restrict__ dstW, __bf16* __restrict__ Xb) {
  int bid = blockIdx.x, t = threadIdx.x;
  if (bid < 2560) {
    __shared__ __bf16 tl[32][132];   // [n][k], pad 4 (stride 264B)
    int k0 = (bid & 15) * 128;
    int n0 = (bid >> 4) * 32;
    const float* src;
    int N, c0;
    if (n0 < 2048)      { src = Wq; N = 2048; c0 = n0; }
    else if (n0 < 2560) { src = Wk; N = 512;  c0 = n0 - 2048; }
    else if (n0 < 3072) { src = Wv; N = 512;  c0 = n0 - 2560; }
    else                { src = Wo; N = 2048; c0 = n0 - 3072; }
    int rr = t >> 3;          // 0..31 row within pass
    int cc = (t & 7) * 4;     // col group
#pragma unroll
    for (int pass = 0; pass < 4; ++pass) {
      int k = pass * 32 + rr;
      float4 v = *(const float4*)(src + (size_t)(k0 + k) * N + c0 + cc);
      tl[cc + 0][k] = (__bf16)v.x;
      tl[cc + 1][k] = (__bf16)v.y;
      tl[cc + 2][k] = (__bf16)v.z;
      tl[cc + 3][k] = (__bf16)v.w;
    }
    __syncthreads();
    int n = t >> 4;           // 0..15
    int ch = t & 15;          // k-chunk (8 elems = 16B)
#pragma unroll
    for (int it = 0; it < 2; ++it) {
      int nn = n + it * 16;
      s16x4 lo = *(const s16x4*)(&tl[nn][ch * 8]);
      s16x4 hi = *(const s16x4*)(&tl[nn][ch * 8 + 4]);
      s16x8 o = __builtin_shufflevector(lo, hi, 0, 1, 2, 3, 4, 5, 6, 7);
      *(s16x8*)(dstW + (size_t)(n0 + nn) * HIDDEN + k0 + ch * 8) = o;
    }
  } else {
    size_t i = (size_t)(bid - 2560) * 256 + t;   // 16 elems per thread
    const float4* s = (const float4*)(x + i * 16);
    float4 a = s[0], b = s[1], c = s[2], d = s[3];
    bf16x8 o0, o1;
    o0[0] = (__bf16)a.x; o0[1] = (__bf16)a.y; o0[2] = (__bf16)a.z; o0[3] = (__bf16)a.w;
    o0[4] = (__bf16)b.x; o0[5] = (__bf16)b.y; o0[6] = (__bf16)b.z; o0[7] = (__bf16)b.w;
    o1[0] = (__bf16)c.x; o1[1] = (__bf16)c.y; o1[2] = (__bf16)c.z; o1[3] = (__bf16)c.w;
    o1[4] = (__bf16)d.x; o1[5] = (__bf16)d.y; o1[6] = (__bf16)d.z; o1[7] = (__bf16)d.w;
    *(bf16x8*)(Xb + i * 16)     = o0;
    *(bf16x8*)(Xb + i * 16 + 8) = o1;
  }
}

// ---------------------------------------------------------------------------
// GEMM: C[M][N] = A[M][K] @ Bt[N][K]^T  (bf16 in, fp32 accum, OutT out)
// 128x128 tile, BK=64 as 2x32 panels, XCD-swizzled 1D grid. (R6 config,
// HW-verified 62us @ QKV.)
// R11: K-chunk swizzle — LDS chunk c of row r holds global chunk c^((r&15)>>1&3)
// via per-lane SOURCE offset (dest linear, G21); reads fetch chunk
// quad^((l16>>1)&3) -> returns global chunk quad (bit-identical math).
// Same transform as flash K (5.57M->0) and 256^2 gemm (0), same geometry.
// ROPE variant (QKV gemm): heads 0..39 rotary fused; heads 40..47 (V)
// written TRANSPOSED into Vt[(b*8+hk)*64+d][s] instead of C.
// ---------------------------------------------------------------------------
template <typename OutT, bool ROPE>
__launch_bounds__(256, 2)
__global__ void gemm_bt(const __bf16* __restrict__ A, const __bf16* __restrict__ Bt,
                        OutT* __restrict__ C, int M, int N, int K,
                        const int* __restrict__ pos_ids, __bf16* __restrict__ Vt) {
  __shared__ __bf16 As[2][128 * 32];
  __shared__ __bf16 Bs[2][128 * 32];
  int id = blockIdx.x;
  int bm = (id & 7) * 4 + ((id >> 3) & 3);
  int bn = id >> 5;
  int t = threadIdx.x;
  int wave = t >> 6, lane = t & 63, l16 = lane & 15, quad = lane >> 4;
  int wm = (wave >> 1) * 64, wn = (wave & 1) * 64;

  f32x4 acc[4][4] = {};

  int arow = t >> 2;                         // 0..63
  int ac   = ((t & 3) ^ ((t >> 3) & 3)) * 8; // SWIZZLED source chunk
  int rq   = (quad ^ ((l16 >> 1) & 3)) * 8;  // swizzled read chunk
  const __bf16* Ag = A  + (size_t)(bm * 128 + arow) * K + ac;
  const __bf16* Bg = Bt + (size_t)(bn * 128 + arow) * K + ac;
  int woff = wave * 512;

  for (int k0 = 0; k0 < K; k0 += 64) {
    __syncthreads();
    gl2lds16(Ag + k0,                      &As[0][woff]);
    gl2lds16(Ag + (size_t)64 * K + k0,      &As[0][2048 + woff]);
    gl2lds16(Ag + k0 + 32,                 &As[1][woff]);
    gl2lds16(Ag + (size_t)64 * K + k0 + 32, &As[1][2048 + woff]);
    gl2lds16(Bg + k0,                      &Bs[0][woff]);
    gl2lds16(Bg + (size_t)64 * K + k0,      &Bs[0][2048 + woff]);
    gl2lds16(Bg + k0 + 32,                 &Bs[1][woff]);
    gl2lds16(Bg + (size_t)64 * K + k0 + 32, &Bs[1][2048 + woff]);
    __syncthreads();

#pragma unroll
    for (int ks = 0; ks < 2; ++ks) {
      bf16x8 af[4], bfr[4];
#pragma unroll
      for (int i = 0; i < 4; ++i) {
        af[i]  = *(const bf16x8*)(&As[ks][(wm + i * 16 + l16) * 32 + rq]);
        bfr[i] = *(const bf16x8*)(&Bs[ks][(wn + i * 16 + l16) * 32 + rq]);
      }
#pragma unroll
      for (int i = 0; i < 4; ++i)
#pragma unroll
        for (int j = 0; j < 4; ++j)
          acc[i][j] = __builtin_amdgcn_mfma_f32_16x16x32_bf16(af[i], bfr[j], acc[i][j], 0, 0, 0);
    }
  }

  if (ROPE) {
    int headidx = bn * 2 + (wn >> 6);   // 64-col head index
    if (headidx >= 40) {
      // V head: write transposed into Vt, skip normal C write
#pragma unroll
      for (int i = 0; i < 4; ++i) {
        int srow = bm * 128 + wm + i * 16 + quad * 4;   // +r, r=0..3 same b
        int b = srow >> 11, s = srow & 2047;
#pragma unroll
        for (int j = 0; j < 4; ++j) {
          int vcol = bn * 128 + wn + j * 16 + l16 - VCOL;
          int hk = vcol >> 6, d = vcol & 63;
          bf16x4 w;
#pragma unroll
          for (int r = 0; r < 4; ++r) w[r] = (__bf16)acc[i][j][r];
          *(bf16x4*)(Vt + ((size_t)(b * NKVH + hk) * HD + d) * SEQ + s) = w;
        }
      }
      return;
    }
    // Q/K heads: rotary
    float invrev0 = __expf(-(float)l16 * 0.28782313662425574f) * 0.15915494309189535f;
    float invrev1 = __expf(-(float)(l16 + 16) * 0.28782313662425574f) * 0.15915494309189535f;
#pragma unroll
    for (int i = 0; i < 4; ++i)
#pragma unroll
      for (int r = 0; r < 4; ++r) {
        int gr = bm * 128 + wm + i * 16 + quad * 4 + r;
        float pos = (float)pos_ids[gr];
        float rv0 = pos * invrev0; rv0 -= floorf(rv0);
        float rv1 = pos * invrev1; rv1 -= floorf(rv1);
        float a0 = rv0 * 6.283185307179586f, a1 = rv1 * 6.283185307179586f;
        float s0 = __sinf(a0), c0 = __cosf(a0);
        float s1 = __sinf(a1), c1 = __cosf(a1);
        float x0 = acc[i][0][r], x2 = acc[i][2][r];
        acc[i][0][r] = x0 * c0 - x2 * s0;
        acc[i][2][r] = x2 * c0 + x0 * s0;
        float x1 = acc[i][1][r], x3 = acc[i][3][r];
        acc[i][1][r] = x1 * c1 - x3 * s1;
        acc[i][3][r] = x3 * c1 + x1 * s1;
      }
  }

#pragma unroll
  for (int i = 0; i < 4; ++i)
#pragma unroll
    for (int j = 0; j < 4; ++j)
#pragma unroll
      for (int r = 0; r < 4; ++r)
        C[(size_t)(bm * 128 + wm + i * 16 + quad * 4 + r) * N +
          (bn * 128 + wn + j * 16 + l16)] = (OutT)acc[i][j][r];
}

// ---------------------------------------------------------------------------
// Flash attention (causal, GQA) — R6 structure (conflict-free verified)
// + s_setprio(1) around MFMA clusters (4 independent blocks/CU = the m191
// role-diversity regime where setprio pays on attn; cannot affect math).
// ---------------------------------------------------------------------------
__launch_bounds__(256, 4)
__global__ void flash_attn(const __bf16* __restrict__ QKV, const __bf16* __restrict__ Vt,
                           __bf16* __restrict__ O) {
  int wgid = blockIdx.x + 64 * (blockIdx.y + 8 * (int)blockIdx.z);
  int xcd  = wgid & 7;          // hardware XCD (round-robin on linear id)
  int j    = wgid >> 3;         // 0..127: position within XCD's sequence
  int G    = j >> 6;            // which of this XCD's 2 KV groups
  int gid  = xcd * 2 + G;       // (b,hk) group id 0..15
  int b    = gid >> 3;
  int hk   = gid & 7;
  int r    = j & 63;            // 0..63: 4 heads x 16 M, balance-coded
  int b0   = r & 1, b5 = (r >> 5) & 1;
  int h    = hk * 4 + b0 + 2 * b5;            // query head
  int M0   = (r >> 1) & 15;
  int M    = (b0 ^ b5) ? (15 - M0) : M0;      // q-block index 0..15
  int NT   = 2 * M + 2;                       // kv-tiles (= stages)

  int t = threadIdx.x;
  int wave = t >> 6, lane = t & 63, l16 = lane & 15, quad = lane >> 4;

  __shared__ __bf16 Ks[2][2][64 * 32];   // [buf][d-half][kr][32]  16KB
  __shared__ __bf16 Vs[2][4096];         // [buf][s4][colswz][4]   16KB

  const __bf16* Kbase = QKV + (size_t)(b * SEQ) * NQKV + KCOL + hk * HD;
  const __bf16* VtB   = Vt + (size_t)(b * NKVH + hk) * HD * SEQ;

  // K staging: row kr, SWIZZLED global col chunk (slot ^ (row>>1)&3)
  int kr  = wave * 16 + (lane >> 2);
  int kcs = ((lane & 3) ^ ((lane >> 3) & 3)) * 8;
  // K read: LDS slot quad ^ ((row>>1)&3), row = nt*16+l16
  int rq  = (quad ^ ((l16 >> 1) & 3)) * 8;

  // V staging maps (per wave: rows wave*16..+15, 16 s per lane)
  int vd   = kr;                       // Vt d-row 0..63
  int vsc  = (lane & 3) * 16;          // s-chunk start
  int vs4w = (lane & 3) * 4;           // first s4 this lane writes
  int vcw4 = (vd ^ (4 * (lane & 3))) * 4;   // swizzled col*4 for writes

  const s16x4 vones = { (short)0x3F80, (short)0x3F80, (short)0x3F80, (short)0x3F80 };

  // Q fragments for both q-halves, pre-scaled by (1/8)*log2(e)
  bf16x8 qfrag[2][2];   // [qi][ks]
#pragma unroll
  for (int qi = 0; qi < 2; ++qi) {
    const __bf16* qp = QKV + (size_t)(b * SEQ + M * 128 + qi * 64 + wave * 16 + l16) * NQKV
                     + h * HD + quad * 8;
    bf16x8 q0 = *(const bf16x8*)qp;
    bf16x8 q1 = *(const bf16x8*)(qp + 32);
#pragma unroll
    for (int e = 0; e < 8; ++e) {
      qfrag[qi][0][e] = (__bf16)((float)q0[e] * 0.18033688011112042f);
      qfrag[qi][1][e] = (__bf16)((float)q1[e] * 0.18033688011112042f);
    }
  }

  f32x4 lacc[2] = { {0.f,0.f,0.f,0.f}, {0.f,0.f,0.f,0.f} };
  f32x4 oacc[2][4];
#pragma unroll
  for (int qi = 0; qi < 2; ++qi)
#pragma unroll
    for (int dt = 0; dt < 4; ++dt) oacc[qi][dt] = (f32x4){0.f, 0.f, 0.f, 0.f};

  // prologue: stage tile 0 into buf 0
  {
    const __bf16* kp = Kbase + (size_t)kr * NQKV + kcs;
    gl2lds16(kp,      &Ks[0][0][wave * 512]);
    gl2lds16(kp + 32, &Ks[0][1][wave * 512]);
    const __bf16* vp = VtB + (size_t)vd * SEQ + vsc;
    s16x8 v0 = __builtin_bit_cast(s16x8, *(const bf16x8*)vp);
    s16x8 v1 = __builtin_bit_cast(s16x8, *(const bf16x8*)(vp + 8));
    *(s16x4*)(&Vs[0][(vs4w + 0) * 256 + vcw4]) = __builtin_shufflevector(v0, v0, 0, 1, 2, 3);
    *(s16x4*)(&Vs[0][(vs4w + 1) * 256 + vcw4]) = __builtin_shufflevector(v0, v0, 4, 5, 6, 7);
    *(s16x4*)(&Vs[0][(vs4w + 2) * 256 + vcw4]) = __builtin_shufflevector(v1, v1, 0, 1, 2, 3);
    *(s16x4*)(&Vs[0][(vs4w + 3) * 256 + vcw4]) = __builtin_shufflevector(v1, v1, 4, 5, 6, 7);
  }

  for (int kt = 0; kt < NT; ++kt) {
    int buf = kt & 1;
    __syncthreads();   // prefetch of tile kt drained; buf^1 free to fill

    bool pre = (kt < NT - 1);   // also == "qi0 active" (qi0 needs kt <= 2M)
    s16x8 pv0, pv1;
    if (pre) {
      const __bf16* kp = Kbase + (size_t)((kt + 1) * 64 + kr) * NQKV + kcs;
      gl2lds16(kp,      &Ks[buf ^ 1][0][wave * 512]);
      gl2lds16(kp + 32, &Ks[buf ^ 1][1][wave * 512]);
      const __bf16* vp = VtB + (size_t)vd * SEQ + (kt + 1) * 64 + vsc;
      pv0 = __builtin_bit_cast(s16x8, *(const bf16x8*)vp);
      pv1 = __builtin_bit_cast(s16x8, *(const bf16x8*)(vp + 8));
    }

    // ---- S^T = K Q^T : D[k=quad*4+r][q=l16], both q-halves share kf ----
    f32x4 s0[4], s1[4];
#pragma unroll
    for (int nt = 0; nt < 4; ++nt) {
      s0[nt] = (f32x4){0.f, 0.f, 0.f, 0.f};
      s1[nt] = (f32x4){0.f, 0.f, 0.f, 0.f};
    }
#pragma unroll
    for (int ks = 0; ks < 2; ++ks) {
      bf16x8 kf[4];
#pragma unroll
      for (int nt = 0; nt < 4; ++nt)
        kf[nt] = *(const bf16x8*)(&Ks[buf][ks][(nt * 16 + l16) * 32 + rq]);
      __builtin_amdgcn_s_setprio(1);
#pragma unroll
      for (int nt = 0; nt < 4; ++nt)
        s1[nt] = __builtin_amdgcn_mfma_f32_16x16x32_bf16(kf[nt], qfrag[1][ks], s1[nt], 0, 0, 0);
      if (pre) {
#pragma unroll
        for (int nt = 0; nt < 4; ++nt)
          s0[nt] = __builtin_amdgcn_mfma_f32_16x16x32_bf16(kf[nt], qfrag[0][ks], s0[nt], 0, 0, 0);
      }
      __builtin_amdgcn_s_setprio(0);
    }

    // ---- p = exp2(s^T); pack A-frags for K=16 PV ----
    s16x4 af0[4], af1[4];
    {
      int qg = wave * 16 + l16;
      if (kt == NT - 1) {
#pragma unroll
        for (int nt = 0; nt < 4; ++nt)
#pragma unroll
          for (int rr = 0; rr < 4; ++rr) {
            int kg = nt * 16 + quad * 4 + rr;
            af1[nt][rr] = f2bs(fexp2((kg > qg) ? -1e30f : s1[nt][rr]));
          }
      } else {
#pragma unroll
        for (int nt = 0; nt < 4; ++nt)
#pragma unroll
          for (int rr = 0; rr < 4; ++rr)
            af1[nt][rr] = f2bs(fexp2(s1[nt][rr]));
      }
      if (pre) {
        if (kt == NT - 2) {
#pragma unroll
          for (int nt = 0; nt < 4; ++nt)
#pragma unroll
            for (int rr = 0; rr < 4; ++rr) {
              int kg = nt * 16 + quad * 4 + rr;
              af0[nt][rr] = f2bs(fexp2((kg > qg) ? -1e30f : s0[nt][rr]));
            }
        } else {
#pragma unroll
          for (int nt = 0; nt < 4; ++nt)
#pragma unroll
            for (int rr = 0; rr < 4; ++rr)
              af0[nt][rr] = f2bs(fexp2(s0[nt][rr]));
        }
      }
    }

    // ---- O += P @ V ; row-sum += P @ 1 (both q-halves share vf) ----
#pragma unroll
    for (int nt = 0; nt < 4; ++nt) {
      s16x4 vf[4];
#pragma unroll
      for (int dt = 0; dt < 4; ++dt)
        vf[dt] = *(const s16x4*)(&Vs[buf][(nt * 4 + quad) * 256 +
                                          (((dt * 16 + l16) ^ (nt * 4)) * 4)]);
      __builtin_amdgcn_s_setprio(1);
#pragma unroll
      for (int dt = 0; dt < 4; ++dt)
        oacc[1][dt] = mfma16(af1[nt], vf[dt], oacc[1][dt]);
      lacc[1] = mfma16(af1[nt], vones, lacc[1]);
      if (pre) {
#pragma unroll
        for (int dt = 0; dt < 4; ++dt)
          oacc[0][dt] = mfma16(af0[nt], vf[dt], oacc[0][dt]);
        lacc[0] = mfma16(af0[nt], vones, lacc[0]);
      }
      __builtin_amdgcn_s_setprio(0);
    }

    // ---- deferred V ds_write for tile kt+1 (loads had whole tile) ----
    if (pre) {
      *(s16x4*)(&Vs[buf ^ 1][(vs4w + 0) * 256 + vcw4]) = __builtin_shufflevector(pv0, pv0, 0, 1, 2, 3);
      *(s16x4*)(&Vs[buf ^ 1][(vs4w + 1) * 256 + vcw4]) = __builtin_shufflevector(pv0, pv0, 4, 5, 6, 7);
      *(s16x4*)(&Vs[buf ^ 1][(vs4w + 2) * 256 + vcw4]) = __builtin_shufflevector(pv1, pv1, 0, 1, 2, 3);
      *(s16x4*)(&Vs[buf ^ 1][(vs4w + 3) * 256 + vcw4]) = __builtin_shufflevector(pv1, pv1, 4, 5, 6, 7);
    }
  }

  // epilogue: lane-local normalization (lacc C-layout == oacc C-layout)
#pragma unroll
  for (int qi = 0; qi < 2; ++qi) {
#pragma unroll
    for (int rr = 0; rr < 4; ++rr) {
      float inv = 1.0f / lacc[qi][rr];
#pragma unroll
      for (int dt = 0; dt < 4; ++dt) {
        float o = oacc[qi][dt][rr] * inv;
        O[(size_t)(b * SEQ + M * 128 + qi * 64 + wave * 16 + quad * 4 + rr) * HIDDEN +
          h * HD + dt * 16 + l16] = (__bf16)o;
      }
    }
  }
}

// ---------------------------------------------------------------------------
extern "C" void kernel_launch(void* const* d_in, const int* in_sizes, int n_in,
                              void* d_out, int out_size, void* d_ws, size_t ws_size,
                              hipStream_t stream) {
  const float* x  = (const float*)d_in[0];
  const float* Wq = (const float*)d_in[1];
  const float* Wk = (const float*)d_in[2];
  const float* Wv = (const float*)d_in[3];
  const float* Wo = (const float*)d_in[4];
  const int* pos  = (const int*)d_in[5];

  __bf16* Wqkvt = (__bf16*)d_ws;                       // [5120][2048]: Wqkv^T | Wo^T
  __bf16* Wot   = Wqkvt + (size_t)NQKV * HIDDEN;
  __bf16* Xb    = Wot + (size_t)HIDDEN * HIDDEN;
  __bf16* QKV   = Xb + (size_t)ROWS * HIDDEN;
  __bf16* Oat   = QKV + (size_t)ROWS * NQKV;

  // Vt: own region if workspace allows (removes the Xb-alias write/read race
  // inside the QKV GEMM); alias fallback preserves old behavior otherwise.
  size_t need = ((size_t)(NQKV + HIDDEN) * HIDDEN + 2 * (size_t)ROWS * HIDDEN +
                 (size_t)ROWS * NQKV + (size_t)BATCH * NKVH * HD * SEQ) * sizeof(__bf16);
  __bf16* Vt = (ws_size >= need) ? (Oat + (size_t)ROWS * HIDDEN) : Xb;

  prep<<<dim3(4608), 256, 0, stream>>>(Wq, Wk, Wv, Wo, x, Wqkvt, Xb);

  gemm_bt<__bf16, true><<<dim3(768), 256, 0, stream>>>(
      Xb, Wqkvt, QKV, ROWS, NQKV, HIDDEN, pos, Vt);

  flash_attn<<<dim3(64, NKVH, BATCH), 256, 0, stream>>>(QKV, Vt, Oat);

  gemm_bt<float, false><<<dim3(512), 256, 0, stream>>>(
      Oat, Wot, (float*)d_out, ROWS, HIDDEN, HIDDEN, nullptr, nullptr);
}

// Round 12
// 261.103 us; speedup vs baseline: 1.1636x; 1.0273x over previous
//
#include <hip/hip_runtime.h>
#include <hip/hip_bf16.h>

// Problem constants (Attention_72499047957038)
#define HIDDEN 2048
#define NHEADS 32
#define NKVH   8
#define HD     64
#define BATCH  2
#define SEQ    2048
#define ROWS   (BATCH * SEQ)   // 4096
#define NQKV   3072            // 2048 Q + 512 K + 512 V
#define KCOL   2048
#define VCOL   2560

typedef __bf16 bf16x8 __attribute__((ext_vector_type(8)));
typedef __bf16 bf16x4 __attribute__((ext_vector_type(4)));
typedef float  f32x4  __attribute__((ext_vector_type(4)));
typedef short  s16x4  __attribute__((ext_vector_type(4)));
typedef short  s16x8  __attribute__((ext_vector_type(8)));

// async global->LDS, 16B per lane; LDS dest = wave-uniform base + lane*16
__device__ __forceinline__ void gl2lds16(const void* g, void* l) {
  __builtin_amdgcn_global_load_lds(
      (const __attribute__((address_space(1))) void*)g,
      (__attribute__((address_space(3))) void*)l, 16, 0, 0);
}

__device__ __forceinline__ short f2bs(float f) {
  __bf16 h = (__bf16)f;
  return __builtin_bit_cast(short, h);
}

// raw 2^x (v_exp_f32); large-negative input underflows to 0 (used for mask)
__device__ __forceinline__ float fexp2(float x) {
#if __has_builtin(__builtin_amdgcn_exp2f)
  return __builtin_amdgcn_exp2f(x);
#else
  return exp2f(x);
#endif
}

// K=16 MFMA: P (A, from S^T C-regs) x V (B). Fallback: zero-padded K=32.
__device__ __forceinline__ f32x4 mfma16(s16x4 a, s16x4 b, f32x4 c) {
#if __has_builtin(__builtin_amdgcn_mfma_f32_16x16x16bf16_1k)
  return __builtin_amdgcn_mfma_f32_16x16x16bf16_1k(a, b, c, 0, 0, 0);
#else
  s16x8 a8 = __builtin_shufflevector(a, (s16x4){0,0,0,0}, 0,1,2,3,4,5,6,7);
  s16x8 b8 = __builtin_shufflevector(b, (s16x4){0,0,0,0}, 0,1,2,3,4,5,6,7);
  a8[4]=0;a8[5]=0;a8[6]=0;a8[7]=0; b8[4]=0;b8[5]=0;b8[6]=0;b8[7]=0;
  return __builtin_amdgcn_mfma_f32_16x16x32_bf16(
      __builtin_bit_cast(bf16x8, a8), __builtin_bit_cast(bf16x8, b8), c, 0, 0, 0);
#endif
}

// ---------------------------------------------------------------------------
// prep: merged weight convert+transpose AND x fp32->bf16 convert. (as R6)
// ---------------------------------------------------------------------------
__global__ void prep(const float* __restrict__ Wq, const float* __restrict__ Wk,
                     const float* __restrict__ Wv, const float* __restrict__ Wo,
                     const float* __restrict__ x,
                     __bf16* __restrict__ dstW, __bf16* __restrict__ Xb) {
  int bid = blockIdx.x, t = threadIdx.x;
  if (bid < 2560) {
    __shared__ __bf16 tl[32][132];   // [n][k], pad 4 (stride 264B)
    int k0 = (bid & 15) * 128;
    int n0 = (bid >> 4) * 32;
    const float* src;
    int N, c0;
    if (n0 < 2048)      { src = Wq; N = 2048; c0 = n0; }
    else if (n0 < 2560) { src = Wk; N = 512;  c0 = n0 - 2048; }
    else if (n0 < 3072) { src = Wv; N = 512;  c0 = n0 - 2560; }
    else                { src = Wo; N = 2048; c0 = n0 - 3072; }
    int rr = t >> 3;          // 0..31 row within pass
    int cc = (t & 7) * 4;     // col group
#pragma unroll
    for (int pass = 0; pass < 4; ++pass) {
      int k = pass * 32 + rr;
      float4 v = *(const float4*)(src + (size_t)(k0 + k) * N + c0 + cc);
      tl[cc + 0][k] = (__bf16)v.x;
      tl[cc + 1][k] = (__bf16)v.y;
      tl[cc + 2][k] = (__bf16)v.z;
      tl[cc + 3][k] = (__bf16)v.w;
    }
    __syncthreads();
    int n = t >> 4;           // 0..15
    int ch = t & 15;          // k-chunk (8 elems = 16B)
#pragma unroll
    for (int it = 0; it < 2; ++it) {
      int nn = n + it * 16;
      s16x4 lo = *(const s16x4*)(&tl[nn][ch * 8]);
      s16x4 hi = *(const s16x4*)(&tl[nn][ch * 8 + 4]);
      s16x8 o = __builtin_shufflevector(lo, hi, 0, 1, 2, 3, 4, 5, 6, 7);
      *(s16x8*)(dstW + (size_t)(n0 + nn) * HIDDEN + k0 + ch * 8) = o;
    }
  } else {
    size_t i = (size_t)(bid - 2560) * 256 + t;   // 16 elems per thread
    const float4* s = (const float4*)(x + i * 16);
    float4 a = s[0], b = s[1], c = s[2], d = s[3];
    bf16x8 o0, o1;
    o0[0] = (__bf16)a.x; o0[1] = (__bf16)a.y; o0[2] = (__bf16)a.z; o0[3] = (__bf16)a.w;
    o0[4] = (__bf16)b.x; o0[5] = (__bf16)b.y; o0[6] = (__bf16)b.z; o0[7] = (__bf16)b.w;
    o1[0] = (__bf16)c.x; o1[1] = (__bf16)c.y; o1[2] = (__bf16)c.z; o1[3] = (__bf16)c.w;
    o1[4] = (__bf16)d.x; o1[5] = (__bf16)d.y; o1[6] = (__bf16)d.z; o1[7] = (__bf16)d.w;
    *(bf16x8*)(Xb + i * 16)     = o0;
    *(bf16x8*)(Xb + i * 16 + 8) = o1;
  }
}

// ---------------------------------------------------------------------------
// GEMM: C[M][N] = A[M][K] @ Bt[N][K]^T  (bf16 in, fp32 accum, OutT out)
// 128x128 tile, BK=64 as 2x32 panels, XCD-swizzled 1D grid.
// K-chunk swizzle (R11, verified: QKV dropped below 61.7us): LDS chunk c of
// row r holds global chunk c^(((r&15)>>1)&3) via per-lane SOURCE offset
// (dest linear, G21); reads fetch chunk quad^((l16>>1)&3) -> returns global
// chunk quad (bit-identical math, conflicts ~0).
// ROPE variant (QKV gemm): heads 0..39 rotary fused; heads 40..47 (V)
// written TRANSPOSED into Vt[(b*8+hk)*64+d][s] instead of C.
// ---------------------------------------------------------------------------
template <typename OutT, bool ROPE>
__launch_bounds__(256, 2)
__global__ void gemm_bt(const __bf16* __restrict__ A, const __bf16* __restrict__ Bt,
                        OutT* __restrict__ C, int M, int N, int K,
                        const int* __restrict__ pos_ids, __bf16* __restrict__ Vt) {
  __shared__ __bf16 As[2][128 * 32];
  __shared__ __bf16 Bs[2][128 * 32];
  int id = blockIdx.x;
  int bm = (id & 7) * 4 + ((id >> 3) & 3);
  int bn = id >> 5;
  int t = threadIdx.x;
  int wave = t >> 6, lane = t & 63, l16 = lane & 15, quad = lane >> 4;
  int wm = (wave >> 1) * 64, wn = (wave & 1) * 64;

  f32x4 acc[4][4] = {};

  int arow = t >> 2;                         // 0..63
  int ac   = ((t & 3) ^ ((t >> 3) & 3)) * 8; // SWIZZLED source chunk
  int rq   = (quad ^ ((l16 >> 1) & 3)) * 8;  // swizzled read chunk
  const __bf16* Ag = A  + (size_t)(bm * 128 + arow) * K + ac;
  const __bf16* Bg = Bt + (size_t)(bn * 128 + arow) * K + ac;
  int woff = wave * 512;

  for (int k0 = 0; k0 < K; k0 += 64) {
    __syncthreads();
    gl2lds16(Ag + k0,                      &As[0][woff]);
    gl2lds16(Ag + (size_t)64 * K + k0,      &As[0][2048 + woff]);
    gl2lds16(Ag + k0 + 32,                 &As[1][woff]);
    gl2lds16(Ag + (size_t)64 * K + k0 + 32, &As[1][2048 + woff]);
    gl2lds16(Bg + k0,                      &Bs[0][woff]);
    gl2lds16(Bg + (size_t)64 * K + k0,      &Bs[0][2048 + woff]);
    gl2lds16(Bg + k0 + 32,                 &Bs[1][woff]);
    gl2lds16(Bg + (size_t)64 * K + k0 + 32, &Bs[1][2048 + woff]);
    __syncthreads();

#pragma unroll
    for (int ks = 0; ks < 2; ++ks) {
      bf16x8 af[4], bfr[4];
#pragma unroll
      for (int i = 0; i < 4; ++i) {
        af[i]  = *(const bf16x8*)(&As[ks][(wm + i * 16 + l16) * 32 + rq]);
        bfr[i] = *(const bf16x8*)(&Bs[ks][(wn + i * 16 + l16) * 32 + rq]);
      }
#pragma unroll
      for (int i = 0; i < 4; ++i)
#pragma unroll
        for (int j = 0; j < 4; ++j)
          acc[i][j] = __builtin_amdgcn_mfma_f32_16x16x32_bf16(af[i], bfr[j], acc[i][j], 0, 0, 0);
    }
  }

  if (ROPE) {
    int headidx = bn * 2 + (wn >> 6);   // 64-col head index
    if (headidx >= 40) {
      // V head: write transposed into Vt, skip normal C write
#pragma unroll
      for (int i = 0; i < 4; ++i) {
        int srow = bm * 128 + wm + i * 16 + quad * 4;   // +r, r=0..3 same b
        int b = srow >> 11, s = srow & 2047;
#pragma unroll
        for (int j = 0; j < 4; ++j) {
          int vcol = bn * 128 + wn + j * 16 + l16 - VCOL;
          int hk = vcol >> 6, d = vcol & 63;
          bf16x4 w;
#pragma unroll
          for (int r = 0; r < 4; ++r) w[r] = (__bf16)acc[i][j][r];
          *(bf16x4*)(Vt + ((size_t)(b * NKVH + hk) * HD + d) * SEQ + s) = w;
        }
      }
      return;
    }
    // Q/K heads: rotary
    float invrev0 = __expf(-(float)l16 * 0.28782313662425574f) * 0.15915494309189535f;
    float invrev1 = __expf(-(float)(l16 + 16) * 0.28782313662425574f) * 0.15915494309189535f;
#pragma unroll
    for (int i = 0; i < 4; ++i)
#pragma unroll
      for (int r = 0; r < 4; ++r) {
        int gr = bm * 128 + wm + i * 16 + quad * 4 + r;
        float pos = (float)pos_ids[gr];
        float rv0 = pos * invrev0; rv0 -= floorf(rv0);
        float rv1 = pos * invrev1; rv1 -= floorf(rv1);
        float a0 = rv0 * 6.283185307179586f, a1 = rv1 * 6.283185307179586f;
        float s0 = __sinf(a0), c0 = __cosf(a0);
        float s1 = __sinf(a1), c1 = __cosf(a1);
        float x0 = acc[i][0][r], x2 = acc[i][2][r];
        acc[i][0][r] = x0 * c0 - x2 * s0;
        acc[i][2][r] = x2 * c0 + x0 * s0;
        float x1 = acc[i][1][r], x3 = acc[i][3][r];
        acc[i][1][r] = x1 * c1 - x3 * s1;
        acc[i][3][r] = x3 * c1 + x1 * s1;
      }
  }

#pragma unroll
  for (int i = 0; i < 4; ++i)
#pragma unroll
    for (int j = 0; j < 4; ++j)
#pragma unroll
      for (int r = 0; r < 4; ++r)
        C[(size_t)(bm * 128 + wm + i * 16 + quad * 4 + r) * N +
          (bn * 128 + wn + j * 16 + l16)] = (OutT)acc[i][j][r];
}

// ---------------------------------------------------------------------------
// Flash attention (causal, GQA) — exact R6 structure (session-best, 266.3us
// total, conflict-free verified). R11's setprio wrap REMOVED: the 4-wave
// barrier-synced block is the m190 null/negative regime, not m191's
// independent-block regime; measured cost ~2us.
// ---------------------------------------------------------------------------
__launch_bounds__(256, 4)
__global__ void flash_attn(const __bf16* __restrict__ QKV, const __bf16* __restrict__ Vt,
                           __bf16* __restrict__ O) {
  int wgid = blockIdx.x + 64 * (blockIdx.y + 8 * (int)blockIdx.z);
  int xcd  = wgid & 7;          // hardware XCD (round-robin on linear id)
  int j    = wgid >> 3;         // 0..127: position within XCD's sequence
  int G    = j >> 6;            // which of this XCD's 2 KV groups
  int gid  = xcd * 2 + G;       // (b,hk) group id 0..15
  int b    = gid >> 3;
  int hk   = gid & 7;
  int r    = j & 63;            // 0..63: 4 heads x 16 M, balance-coded
  int b0   = r & 1, b5 = (r >> 5) & 1;
  int h    = hk * 4 + b0 + 2 * b5;            // query head
  int M0   = (r >> 1) & 15;
  int M    = (b0 ^ b5) ? (15 - M0) : M0;      // q-block index 0..15
  int NT   = 2 * M + 2;                       // kv-tiles (= stages)

  int t = threadIdx.x;
  int wave = t >> 6, lane = t & 63, l16 = lane & 15, quad = lane >> 4;

  __shared__ __bf16 Ks[2][2][64 * 32];   // [buf][d-half][kr][32]  16KB
  __shared__ __bf16 Vs[2][4096];         // [buf][s4][colswz][4]   16KB

  const __bf16* Kbase = QKV + (size_t)(b * SEQ) * NQKV + KCOL + hk * HD;
  const __bf16* VtB   = Vt + (size_t)(b * NKVH + hk) * HD * SEQ;

  // K staging: row kr, SWIZZLED global col chunk (slot ^ (row>>1)&3)
  int kr  = wave * 16 + (lane >> 2);
  int kcs = ((lane & 3) ^ ((lane >> 3) & 3)) * 8;
  // K read: LDS slot quad ^ ((row>>1)&3), row = nt*16+l16
  int rq  = (quad ^ ((l16 >> 1) & 3)) * 8;

  // V staging maps (per wave: rows wave*16..+15, 16 s per lane)
  int vd   = kr;                       // Vt d-row 0..63
  int vsc  = (lane & 3) * 16;          // s-chunk start
  int vs4w = (lane & 3) * 4;           // first s4 this lane writes
  int vcw4 = (vd ^ (4 * (lane & 3))) * 4;   // swizzled col*4 for writes

  const s16x4 vones = { (short)0x3F80, (short)0x3F80, (short)0x3F80, (short)0x3F80 };

  // Q fragments for both q-halves, pre-scaled by (1/8)*log2(e)
  bf16x8 qfrag[2][2];   // [qi][ks]
#pragma unroll
  for (int qi = 0; qi < 2; ++qi) {
    const __bf16* qp = QKV + (size_t)(b * SEQ + M * 128 + qi * 64 + wave * 16 + l16) * NQKV
                     + h * HD + quad * 8;
    bf16x8 q0 = *(const bf16x8*)qp;
    bf16x8 q1 = *(const bf16x8*)(qp + 32);
#pragma unroll
    for (int e = 0; e < 8; ++e) {
      qfrag[qi][0][e] = (__bf16)((float)q0[e] * 0.18033688011112042f);
      qfrag[qi][1][e] = (__bf16)((float)q1[e] * 0.18033688011112042f);
    }
  }

  f32x4 lacc[2] = { {0.f,0.f,0.f,0.f}, {0.f,0.f,0.f,0.f} };
  f32x4 oacc[2][4];
#pragma unroll
  for (int qi = 0; qi < 2; ++qi)
#pragma unroll
    for (int dt = 0; dt < 4; ++dt) oacc[qi][dt] = (f32x4){0.f, 0.f, 0.f, 0.f};

  // prologue: stage tile 0 into buf 0
  {
    const __bf16* kp = Kbase + (size_t)kr * NQKV + kcs;
    gl2lds16(kp,      &Ks[0][0][wave * 512]);
    gl2lds16(kp + 32, &Ks[0][1][wave * 512]);
    const __bf16* vp = VtB + (size_t)vd * SEQ + vsc;
    s16x8 v0 = __builtin_bit_cast(s16x8, *(const bf16x8*)vp);
    s16x8 v1 = __builtin_bit_cast(s16x8, *(const bf16x8*)(vp + 8));
    *(s16x4*)(&Vs[0][(vs4w + 0) * 256 + vcw4]) = __builtin_shufflevector(v0, v0, 0, 1, 2, 3);
    *(s16x4*)(&Vs[0][(vs4w + 1) * 256 + vcw4]) = __builtin_shufflevector(v0, v0, 4, 5, 6, 7);
    *(s16x4*)(&Vs[0][(vs4w + 2) * 256 + vcw4]) = __builtin_shufflevector(v1, v1, 0, 1, 2, 3);
    *(s16x4*)(&Vs[0][(vs4w + 3) * 256 + vcw4]) = __builtin_shufflevector(v1, v1, 4, 5, 6, 7);
  }

  for (int kt = 0; kt < NT; ++kt) {
    int buf = kt & 1;
    __syncthreads();   // prefetch of tile kt drained; buf^1 free to fill

    bool pre = (kt < NT - 1);   // also == "qi0 active" (qi0 needs kt <= 2M)
    s16x8 pv0, pv1;
    if (pre) {
      const __bf16* kp = Kbase + (size_t)((kt + 1) * 64 + kr) * NQKV + kcs;
      gl2lds16(kp,      &Ks[buf ^ 1][0][wave * 512]);
      gl2lds16(kp + 32, &Ks[buf ^ 1][1][wave * 512]);
      const __bf16* vp = VtB + (size_t)vd * SEQ + (kt + 1) * 64 + vsc;
      pv0 = __builtin_bit_cast(s16x8, *(const bf16x8*)vp);
      pv1 = __builtin_bit_cast(s16x8, *(const bf16x8*)(vp + 8));
    }

    // ---- S^T = K Q^T : D[k=quad*4+r][q=l16], both q-halves share kf ----
    f32x4 s0[4], s1[4];
#pragma unroll
    for (int nt = 0; nt < 4; ++nt) {
      s0[nt] = (f32x4){0.f, 0.f, 0.f, 0.f};
      s1[nt] = (f32x4){0.f, 0.f, 0.f, 0.f};
    }
#pragma unroll
    for (int ks = 0; ks < 2; ++ks) {
      bf16x8 kf[4];
#pragma unroll
      for (int nt = 0; nt < 4; ++nt)
        kf[nt] = *(const bf16x8*)(&Ks[buf][ks][(nt * 16 + l16) * 32 + rq]);
#pragma unroll
      for (int nt = 0; nt < 4; ++nt)
        s1[nt] = __builtin_amdgcn_mfma_f32_16x16x32_bf16(kf[nt], qfrag[1][ks], s1[nt], 0, 0, 0);
      if (pre) {
#pragma unroll
        for (int nt = 0; nt < 4; ++nt)
          s0[nt] = __builtin_amdgcn_mfma_f32_16x16x32_bf16(kf[nt], qfrag[0][ks], s0[nt], 0, 0, 0);
      }
    }

    // ---- p = exp2(s^T); pack A-frags for K=16 PV ----
    s16x4 af0[4], af1[4];
    {
      int qg = wave * 16 + l16;
      if (kt == NT - 1) {
#pragma unroll
        for (int nt = 0; nt < 4; ++nt)
#pragma unroll
          for (int rr = 0; rr < 4; ++rr) {
            int kg = nt * 16 + quad * 4 + rr;
            af1[nt][rr] = f2bs(fexp2((kg > qg) ? -1e30f : s1[nt][rr]));
          }
      } else {
#pragma unroll
        for (int nt = 0; nt < 4; ++nt)
#pragma unroll
          for (int rr = 0; rr < 4; ++rr)
            af1[nt][rr] = f2bs(fexp2(s1[nt][rr]));
      }
      if (pre) {
        if (kt == NT - 2) {
#pragma unroll
          for (int nt = 0; nt < 4; ++nt)
#pragma unroll
            for (int rr = 0; rr < 4; ++rr) {
              int kg = nt * 16 + quad * 4 + rr;
              af0[nt][rr] = f2bs(fexp2((kg > qg) ? -1e30f : s0[nt][rr]));
            }
        } else {
#pragma unroll
          for (int nt = 0; nt < 4; ++nt)
#pragma unroll
            for (int rr = 0; rr < 4; ++rr)
              af0[nt][rr] = f2bs(fexp2(s0[nt][rr]));
        }
      }
    }

    // ---- O += P @ V ; row-sum += P @ 1 (both q-halves share vf) ----
#pragma unroll
    for (int nt = 0; nt < 4; ++nt) {
      s16x4 vf[4];
#pragma unroll
      for (int dt = 0; dt < 4; ++dt)
        vf[dt] = *(const s16x4*)(&Vs[buf][(nt * 4 + quad) * 256 +
                                          (((dt * 16 + l16) ^ (nt * 4)) * 4)]);
#pragma unroll
      for (int dt = 0; dt < 4; ++dt)
        oacc[1][dt] = mfma16(af1[nt], vf[dt], oacc[1][dt]);
      lacc[1] = mfma16(af1[nt], vones, lacc[1]);
      if (pre) {
#pragma unroll
        for (int dt = 0; dt < 4; ++dt)
          oacc[0][dt] = mfma16(af0[nt], vf[dt], oacc[0][dt]);
        lacc[0] = mfma16(af0[nt], vones, lacc[0]);
      }
    }

    // ---- deferred V ds_write for tile kt+1 (loads had whole tile) ----
    if (pre) {
      *(s16x4*)(&Vs[buf ^ 1][(vs4w + 0) * 256 + vcw4]) = __builtin_shufflevector(pv0, pv0, 0, 1, 2, 3);
      *(s16x4*)(&Vs[buf ^ 1][(vs4w + 1) * 256 + vcw4]) = __builtin_shufflevector(pv0, pv0, 4, 5, 6, 7);
      *(s16x4*)(&Vs[buf ^ 1][(vs4w + 2) * 256 + vcw4]) = __builtin_shufflevector(pv1, pv1, 0, 1, 2, 3);
      *(s16x4*)(&Vs[buf ^ 1][(vs4w + 3) * 256 + vcw4]) = __builtin_shufflevector(pv1, pv1, 4, 5, 6, 7);
    }
  }

  // epilogue: lane-local normalization (lacc C-layout == oacc C-layout)
#pragma unroll
  for (int qi = 0; qi < 2; ++qi) {
#pragma unroll
    for (int rr = 0; rr < 4; ++rr) {
      float inv = 1.0f / lacc[qi][rr];
#pragma unroll
      for (int dt = 0; dt < 4; ++dt) {
        float o = oacc[qi][dt][rr] * inv;
        O[(size_t)(b * SEQ + M * 128 + qi * 64 + wave * 16 + quad * 4 + rr) * HIDDEN +
          h * HD + dt * 16 + l16] = (__bf16)o;
      }
    }
  }
}

// ---------------------------------------------------------------------------
extern "C" void kernel_launch(void* const* d_in, const int* in_sizes, int n_in,
                              void* d_out, int out_size, void* d_ws, size_t ws_size,
                              hipStream_t stream) {
  const float* x  = (const float*)d_in[0];
  const float* Wq = (const float*)d_in[1];
  const float* Wk = (const float*)d_in[2];
  const float* Wv = (const float*)d_in[3];
  const float* Wo = (const float*)d_in[4];
  const int* pos  = (const int*)d_in[5];

  __bf16* Wqkvt = (__bf16*)d_ws;                       // [5120][2048]: Wqkv^T | Wo^T
  __bf16* Wot   = Wqkvt + (size_t)NQKV * HIDDEN;
  __bf16* Xb    = Wot + (size_t)HIDDEN * HIDDEN;
  __bf16* QKV   = Xb + (size_t)ROWS * HIDDEN;
  __bf16* Oat   = QKV + (size_t)ROWS * NQKV;

  // Vt: own region if workspace allows (removes the Xb-alias write/read race
  // inside the QKV GEMM); alias fallback preserves old behavior otherwise.
  size_t need = ((size_t)(NQKV + HIDDEN) * HIDDEN + 2 * (size_t)ROWS * HIDDEN +
                 (size_t)ROWS * NQKV + (size_t)BATCH * NKVH * HD * SEQ) * sizeof(__bf16);
  __bf16* Vt = (ws_size >= need) ? (Oat + (size_t)ROWS * HIDDEN) : Xb;

  prep<<<dim3(4608), 256, 0, stream>>>(Wq, Wk, Wv, Wo, x, Wqkvt, Xb);

  gemm_bt<__bf16, true><<<dim3(768), 256, 0, stream>>>(
      Xb, Wqkvt, QKV, ROWS, NQKV, HIDDEN, pos, Vt);

  flash_attn<<<dim3(64, NKVH, BATCH), 256, 0, stream>>>(QKV, Vt, Oat);

  gemm_bt<float, false><<<dim3(512), 256, 0, stream>>>(
      Oat, Wot, (float*)d_out, ROWS, HIDDEN, HIDDEN, nullptr, nullptr);
}